// Round 2
// baseline (2182.459 us; speedup 1.0000x reference)
//
#include <hip/hip_runtime.h>

// Problem constants (Go 19x19, B=256, history_factor=10)
#define BB 256
#define HH 19
#define WW 19
#define HW 361            // H*W
#define MAXM 3610         // MAX_MOVES

constexpr unsigned PERB = (unsigned)MAXM * (unsigned)HW;   // 1,303,210 elems per batch
constexpr unsigned TOT  = (unsigned)BB * PERB;             // 333,621,760
constexpr unsigned N4   = TOT / 4u;                        // 83,405,440 vec4s
// Output layout (floats, concatenated in reference return order)
constexpr unsigned OFF_BOARD = 0;                          // B*HW
constexpr unsigned OFF_HIST  = (unsigned)BB * HW;          // 92,416 (16B aligned)
constexpr unsigned OFF_KO    = OFF_HIST + TOT;             // B*2
constexpr unsigned OFF_PASS  = OFF_KO + 2u * BB;           // B
constexpr unsigned OFF_MV    = OFF_PASS + (unsigned)BB;    // B
constexpr unsigned OFF_PL    = OFF_MV + (unsigned)BB;      // B

constexpr unsigned COPY_BLOCKS = 2048;                     // 8 blocks/CU, 32 waves/CU

typedef int   i32x4 __attribute__((ext_vector_type(4)));
typedef float f32x4 __attribute__((ext_vector_type(4)));

__device__ __forceinline__ float state_of(float v) {
  // where(v==0, 0, where(v==1, 1, -1))
  return (v == 0.0f) ? 0.0f : ((v == 1.0f) ? 1.0f : -1.0f);
}

// Pure streaming cast-copy: int32 history -> float32 output history.
// No division, no gathers, no branches. The one row per batch that must be
// replaced with board_state is overwritten afterwards by batch_kernel
// (256*361*4 B = 370 KB of redundant writes, negligible vs 1.33 GB).
__global__ void __launch_bounds__(256) copy_kernel(
    const i32x4* __restrict__ src, f32x4* __restrict__ dst)
{
  unsigned tid    = blockIdx.x * 256u + threadIdx.x;
  unsigned stride = gridDim.x * 256u;
  unsigned i = tid;
  // 4-deep MLP: each load instruction is wave-contiguous (1 KB/instr)
  for (; i + 3u * stride < N4; i += 4u * stride) {
    i32x4 a = __builtin_nontemporal_load(src + i);
    i32x4 b = __builtin_nontemporal_load(src + i + stride);
    i32x4 c = __builtin_nontemporal_load(src + i + 2u * stride);
    i32x4 d = __builtin_nontemporal_load(src + i + 3u * stride);
    __builtin_nontemporal_store(__builtin_convertvector(a, f32x4), dst + i);
    __builtin_nontemporal_store(__builtin_convertvector(b, f32x4), dst + i + stride);
    __builtin_nontemporal_store(__builtin_convertvector(c, f32x4), dst + i + 2u * stride);
    __builtin_nontemporal_store(__builtin_convertvector(d, f32x4), dst + i + 3u * stride);
  }
  for (; i < N4; i += stride) {
    i32x4 a = __builtin_nontemporal_load(src + i);
    __builtin_nontemporal_store(__builtin_convertvector(a, f32x4), dst + i);
  }
}

// Per-batch: board update/capture/ko/scalars + history mv_c row fixup.
// One block per batch. Runs after copy_kernel on the same stream.
__global__ void __launch_bounds__(128) batch_kernel(
    const float* __restrict__ board, const int* __restrict__ cur,
    const int* __restrict__ ko_pts, const int* __restrict__ pass_cnt,
    const int* __restrict__ mvcnt, const int* __restrict__ positions,
    const int* __restrict__ roots, const int* __restrict__ colour,
    const int* __restrict__ cap_groups, const int* __restrict__ cap_sizes,
    const int* __restrict__ total_caps, float* __restrict__ out)
{
  int b = blockIdx.x;
  int t = threadIdx.x;

  int p0 = positions[2 * b], p1 = positions[2 * b + 1];
  bool is_pass = (p0 < 0) || (p1 < 0);
  bool play = !is_pass;
  int row = p0 < 0 ? 0 : (p0 > HH - 1 ? HH - 1 : p0);
  int col = p1 < 0 ? 0 : (p1 > WW - 1 ? WW - 1 : p1);
  int fp = row * WW + col;
  int cp = cur[b];
  int opp = 1 - cp;
  int cgbase = (b * HW + fp) * 4;
  int nr0 = cap_groups[cgbase + 0];
  int nr1 = cap_groups[cgbase + 1];
  int nr2 = cap_groups[cgbase + 2];
  int nr3 = cap_groups[cgbase + 3];

  // history row fixup parameters
  int mv = mvcnt[b];
  bool valid = (mv < MAXM);
  int mvc = mv < 0 ? 0 : (mv >= MAXM ? MAXM - 1 : mv);
  float* hrow = out + OFF_HIST + (size_t)b * PERB + (size_t)mvc * (size_t)HW;

  for (int p = t; p < HW; p += blockDim.x) {
    float v = board[b * HW + p];
    // history board_state for the written row
    if (valid) hrow[p] = state_of(v);
    // place + capture
    float placed = (play && p == fp) ? (float)cp : v;
    int r = roots[b * HW + p];
    bool eq = (nr0 >= 0 && r == nr0) || (nr1 >= 0 && r == nr1) ||
              (nr2 >= 0 && r == nr2) || (nr3 >= 0 && r == nr3);
    bool cap = eq && (colour[b * HW + p] == opp) && play;
    out[OFF_BOARD + b * HW + p] = cap ? -1.0f : placed;
  }

  if (t == 0) {
    // ko from single-stone capture
    int tc = total_caps[b * HW + fp];
    bool single_cap = (tc == 1) && play;
    int s0 = cap_sizes[cgbase + 0];
    int s1 = cap_sizes[cgbase + 1];
    int s2 = cap_sizes[cgbase + 2];
    int s3 = cap_sizes[cgbase + 3];
    // argmax of (sizes==1): first index where true, else 0
    int dir = (s0 == 1) ? 0 : ((s1 == 1) ? 1 : ((s2 == 1) ? 2 : ((s3 == 1) ? 3 : 0)));
    const int offs[4] = {-WW, WW, -1, 1};
    int nbr = fp + offs[dir];
    // Python floor division / mod (nbr can be negative)
    int rko = (nbr >= 0) ? (nbr / WW) : -(((-nbr) + WW - 1) / WW);
    int cko = nbr - rko * WW;

    int okr, okc;
    if (is_pass) { okr = ko_pts[2 * b]; okc = ko_pts[2 * b + 1]; }
    else if (single_cap) { okr = rko; okc = cko; }
    else { okr = -1; okc = -1; }
    out[OFF_KO + 2 * b + 0] = (float)okr;
    out[OFF_KO + 2 * b + 1] = (float)okc;
    out[OFF_PASS + b] = (float)(is_pass ? pass_cnt[b] + 1 : 0);
    out[OFF_MV + b]   = (float)(mvcnt[b] + 1);
    out[OFF_PL + b]   = (float)(cp ^ 1);
  }
}

extern "C" void kernel_launch(void* const* d_in, const int* in_sizes, int n_in,
                              void* d_out, int out_size, void* d_ws, size_t ws_size,
                              hipStream_t stream) {
  const float* board      = (const float*)d_in[0];
  const int*   cur        = (const int*)d_in[1];
  const int*   ko_pts     = (const int*)d_in[2];
  const int*   pass_cnt   = (const int*)d_in[3];
  const int*   hist       = (const int*)d_in[4];
  const int*   mvcnt      = (const int*)d_in[5];
  const int*   positions  = (const int*)d_in[6];
  const int*   roots      = (const int*)d_in[7];
  const int*   colour     = (const int*)d_in[8];
  const int*   cap_groups = (const int*)d_in[9];
  const int*   cap_sizes  = (const int*)d_in[10];
  const int*   total_caps = (const int*)d_in[11];
  float* out = (float*)d_out;

  hipLaunchKernelGGL(copy_kernel, dim3(COPY_BLOCKS), dim3(256), 0, stream,
                     (const i32x4*)hist, (f32x4*)(out + OFF_HIST));
  hipLaunchKernelGGL(batch_kernel, dim3(BB), dim3(128), 0, stream,
                     board, cur, ko_pts, pass_cnt, mvcnt, positions, roots,
                     colour, cap_groups, cap_sizes, total_caps, out);
}